// Round 4
// baseline (275.916 us; speedup 1.0000x reference)
//
#include <hip/hip_runtime.h>

#define BATCH 262144

typedef __attribute__((ext_vector_type(8))) short short8;
typedef __attribute__((ext_vector_type(4))) short s16x4;
typedef __attribute__((ext_vector_type(4))) float f32x4;

// float -> bf16 bits, round-to-nearest-even
static __device__ __forceinline__ short f2b(float f) {
    unsigned u = __float_as_uint(f);
    return (short)((u + 0x7fffu + ((u >> 16) & 1u)) >> 16);
}
static __device__ __forceinline__ float b2f(short s) {
    return __uint_as_float(((unsigned)(unsigned short)s) << 16);
}
static __device__ __forceinline__ float sigm(float x) { return 1.0f / (1.0f + __expf(-x)); }
static __device__ __forceinline__ float tanh_f(float x) { return 1.0f - 2.0f / (__expf(2.0f * x) + 1.0f); }

// All LDS buffers are PER-WAVE: no cross-wave sharing -> no __syncthreads needed.
// DS ops complete in order within a wave; lgkmcnt(0) makes prior ds_writes visible.
#define WAVE_FENCE() asm volatile("s_waitcnt lgkmcnt(0)" ::: "memory")

// XOR swizzle: unpadded rows, slot permutation per row -> 2 rows/slot = free 2-way.
// [16][64] bf16 tile: row stride 128 B.  [16][128] bf16 tile: row stride 256 B.
static __device__ __forceinline__ int sw128(int row, int cb) { return row * 128 + (cb ^ ((row & 7) << 4)); }
static __device__ __forceinline__ int sw256(int row, int cb) { return row * 256 + (cb ^ ((row & 7) << 4)); }

// Convert all weight matrices to bf16 in workspace.
// layout (bf16 elems): [0:8192) w1, [8192:12288) w2, [12288:24576) w_ih,
//                      [24576:36864) w_hh, [36864:45056) lp_w1
__global__ void prep_weights(const float* __restrict__ w1, const float* __restrict__ w2,
                             const float* __restrict__ wih, const float* __restrict__ whh,
                             const float* __restrict__ lw1, unsigned short* __restrict__ wsb) {
    int i = blockIdx.x * 256 + threadIdx.x;
    float v;
    if (i < 8192) v = w1[i];
    else if (i < 12288) v = w2[i - 8192];
    else if (i < 24576) v = wih[i - 12288];
    else if (i < 36864) v = whh[i - 24576];
    else if (i < 45056) v = lw1[i - 36864];
    else return;
    wsb[i] = (unsigned short)f2b(v);
}

__global__ __launch_bounds__(256, 5) void tgn_kernel(
    const int* __restrict__ pairs, const float* __restrict__ memory,
    const unsigned short* __restrict__ wsb,
    const float* __restrict__ b1, const float* __restrict__ b2,
    const float* __restrict__ bih, const float* __restrict__ bhh,
    const float* __restrict__ lb1, const float* __restrict__ lw2,
    const float* __restrict__ lb2, float* __restrict__ out)
{
    // 16384 + 16384 = 32768 B total -> 5 blocks/CU (5 * 32768 = 163840 = full pool)
    __shared__ __align__(16) char nmem[4][2][2048];  // n1/n2: [16][64] bf16 swizzled
    __shared__ __align__(16) char scr[4][4096];      // h1@0, msg@2048 ([16][64]); comb [16][128] overlays

    const int tid = threadIdx.x;
    const int w  = tid >> 6;
    const int l  = tid & 63;
    const int lr = l & 15;       // M/N index within fragment
    const int lg = l >> 4;       // k-group / row-group

    const int r0 = (blockIdx.x * 4 + w) * 16;

    char* n1b  = &nmem[w][0][0];
    char* n2b  = &nmem[w][1][0];
    char* h1b  = &scr[w][0];
    char* msgb = &scr[w][2048];
    char* comb = &scr[w][0];

    const unsigned short* w1b  = wsb;          // [64][128]
    const unsigned short* w2b  = wsb + 8192;   // [64][64]
    const unsigned short* wihb = wsb + 12288;  // [192][64]
    const unsigned short* whhb = wsb + 24576;  // [192][64]
    const unsigned short* lw1b = wsb + 36864;  // [64][128]

    const f32x4 z4 = {0.0f, 0.0f, 0.0f, 0.0f};

    // ---- stage 0: gather -> bf16 LDS. 16 lanes fetch one 256B memory row each ----
#pragma unroll
    for (int rr = 0; rr < 4; ++rr) {
        int row = rr * 4 + lg;
        long i1 = pairs[(r0 + row) * 2 + 0];
        long i2 = pairs[(r0 + row) * 2 + 1];
        f32x4 v1 = *(const f32x4*)(memory + i1 * 64 + lr * 4);
        f32x4 v2 = *(const f32x4*)(memory + i2 * 64 + lr * 4);
        s16x4 c1, c2;
#pragma unroll
        for (int j = 0; j < 4; ++j) { c1[j] = f2b(v1[j]); c2[j] = f2b(v2[j]); }
        int off = sw128(row, lr * 8);
        *(s16x4*)(n1b + off) = c1;
        *(s16x4*)(n2b + off) = c2;
    }
    WAVE_FENCE();

    // ---- stage 1: H1 = relu(X @ w1^T + b1), X = [n1|n2] (16x128) ----
    f32x4 acc[4];
#pragma unroll
    for (int nt = 0; nt < 4; ++nt) acc[nt] = z4;
#pragma unroll
    for (int kt = 0; kt < 4; ++kt) {
        const char* base = (kt < 2) ? n1b : n2b;
        short8 a = *(const short8*)(base + sw128(lr, (kt & 1) * 64 + lg * 16));
#pragma unroll
        for (int nt = 0; nt < 4; ++nt) {
            short8 b = *(const short8*)(w1b + (nt * 16 + lr) * 128 + kt * 32 + lg * 8);
            acc[nt] = __builtin_amdgcn_mfma_f32_16x16x32_bf16(a, b, acc[nt], 0, 0, 0);
        }
    }
#pragma unroll
    for (int nt = 0; nt < 4; ++nt) {
        float bv = b1[nt * 16 + lr];
#pragma unroll
        for (int r = 0; r < 4; ++r) {
            int row = lg * 4 + r;
            *(short*)(h1b + sw128(row, nt * 32 + lr * 2)) = f2b(fmaxf(acc[nt][r] + bv, 0.0f));
        }
    }
    WAVE_FENCE();

    // ---- stage 2: MSG = H1 @ w2^T + b2 (16x64) ----
#pragma unroll
    for (int nt = 0; nt < 4; ++nt) acc[nt] = z4;
#pragma unroll
    for (int kt = 0; kt < 2; ++kt) {
        short8 a = *(const short8*)(h1b + sw128(lr, kt * 64 + lg * 16));
#pragma unroll
        for (int nt = 0; nt < 4; ++nt) {
            short8 b = *(const short8*)(w2b + (nt * 16 + lr) * 64 + kt * 32 + lg * 8);
            acc[nt] = __builtin_amdgcn_mfma_f32_16x16x32_bf16(a, b, acc[nt], 0, 0, 0);
        }
    }
#pragma unroll
    for (int nt = 0; nt < 4; ++nt) {
        float bv = b2[nt * 16 + lr];
#pragma unroll
        for (int r = 0; r < 4; ++r) {
            int row = lg * 4 + r;
            *(short*)(msgb + sw128(row, nt * 32 + lr * 2)) = f2b(acc[nt][r] + bv);
        }
    }
    WAVE_FENCE();

    // ---- stage 3+4 fused: per column-block nt, compute 9 gate tiles then GRU ----
    short8 am[2], a1[2], a2[2];
#pragma unroll
    for (int kt = 0; kt < 2; ++kt) {
        am[kt] = *(const short8*)(msgb + sw128(lr, kt * 64 + lg * 16));
        a1[kt] = *(const short8*)(n1b + sw128(lr, kt * 64 + lg * 16));
        a2[kt] = *(const short8*)(n2b + sw128(lr, kt * 64 + lg * 16));
    }
#pragma unroll
    for (int nt = 0; nt < 4; ++nt) {
        f32x4 gir = z4, giz = z4, gin = z4;
        f32x4 g1r = z4, g1z = z4, g1n = z4;
        f32x4 g2r = z4, g2z = z4, g2n = z4;
#pragma unroll
        for (int kt = 0; kt < 2; ++kt) {
            int ko = kt * 32 + lg * 8;
            short8 bir = *(const short8*)(wihb + ((0 + nt) * 16 + lr) * 64 + ko);
            short8 biz = *(const short8*)(wihb + ((4 + nt) * 16 + lr) * 64 + ko);
            short8 bin = *(const short8*)(wihb + ((8 + nt) * 16 + lr) * 64 + ko);
            short8 bhr = *(const short8*)(whhb + ((0 + nt) * 16 + lr) * 64 + ko);
            short8 bhz = *(const short8*)(whhb + ((4 + nt) * 16 + lr) * 64 + ko);
            short8 bhn = *(const short8*)(whhb + ((8 + nt) * 16 + lr) * 64 + ko);
            gir = __builtin_amdgcn_mfma_f32_16x16x32_bf16(am[kt], bir, gir, 0, 0, 0);
            giz = __builtin_amdgcn_mfma_f32_16x16x32_bf16(am[kt], biz, giz, 0, 0, 0);
            gin = __builtin_amdgcn_mfma_f32_16x16x32_bf16(am[kt], bin, gin, 0, 0, 0);
            g1r = __builtin_amdgcn_mfma_f32_16x16x32_bf16(a1[kt], bhr, g1r, 0, 0, 0);
            g1z = __builtin_amdgcn_mfma_f32_16x16x32_bf16(a1[kt], bhz, g1z, 0, 0, 0);
            g1n = __builtin_amdgcn_mfma_f32_16x16x32_bf16(a1[kt], bhn, g1n, 0, 0, 0);
            g2r = __builtin_amdgcn_mfma_f32_16x16x32_bf16(a2[kt], bhr, g2r, 0, 0, 0);
            g2z = __builtin_amdgcn_mfma_f32_16x16x32_bf16(a2[kt], bhz, g2z, 0, 0, 0);
            g2n = __builtin_amdgcn_mfma_f32_16x16x32_bf16(a2[kt], bhn, g2n, 0, 0, 0);
        }
        int j = nt * 16 + lr;
        float bir_ = bih[j], biz_ = bih[64 + j], bin_ = bih[128 + j];
        float bhr_ = bhh[j], bhz_ = bhh[64 + j], bhn_ = bhh[128 + j];
#pragma unroll
        for (int r = 0; r < 4; ++r) {
            int row = lg * 4 + r;
            float i_r = gir[r] + bir_;
            float i_z = giz[r] + biz_;
            float i_n = gin[r] + bin_;
            // node 1
            float rg = sigm(i_r + g1r[r] + bhr_);
            float zg = sigm(i_z + g1z[r] + bhz_);
            float ng = tanh_f(i_n + rg * (g1n[r] + bhn_));
            float h  = b2f(*(const short*)(n1b + sw128(row, j * 2)));
            *(short*)(comb + sw256(row, j * 2)) = f2b((1.0f - zg) * ng + zg * h);
            // node 2
            rg = sigm(i_r + g2r[r] + bhr_);
            zg = sigm(i_z + g2z[r] + bhz_);
            ng = tanh_f(i_n + rg * (g2n[r] + bhn_));
            h  = b2f(*(const short*)(n2b + sw128(row, j * 2)));
            *(short*)(comb + sw256(row, 128 + j * 2)) = f2b((1.0f - zg) * ng + zg * h);
        }
    }
    WAVE_FENCE();

    // ---- stage 5: H = relu(COMB @ lp_w1^T + lb1) (16x64) ----
    f32x4 acc5[4];
#pragma unroll
    for (int nt = 0; nt < 4; ++nt) acc5[nt] = z4;
#pragma unroll
    for (int kt = 0; kt < 4; ++kt) {
        short8 a = *(const short8*)(comb + sw256(lr, kt * 64 + lg * 16));
#pragma unroll
        for (int nt = 0; nt < 4; ++nt) {
            short8 b = *(const short8*)(lw1b + (nt * 16 + lr) * 128 + kt * 32 + lg * 8);
            acc5[nt] = __builtin_amdgcn_mfma_f32_16x16x32_bf16(a, b, acc5[nt], 0, 0, 0);
        }
    }

    // ---- stage 6: out = sigmoid(H @ lp_w2^T + lb2), reduce over 64 cols ----
    float part[4] = {0.0f, 0.0f, 0.0f, 0.0f};
#pragma unroll
    for (int nt = 0; nt < 4; ++nt) {
        float w2v = lw2[nt * 16 + lr];
        float bv  = lb1[nt * 16 + lr];
#pragma unroll
        for (int r = 0; r < 4; ++r)
            part[r] += fmaxf(acc5[nt][r] + bv, 0.0f) * w2v;
    }
    float lb2v = lb2[0];
#pragma unroll
    for (int r = 0; r < 4; ++r) {
        float p = part[r];
        p += __shfl_xor(p, 1);
        p += __shfl_xor(p, 2);
        p += __shfl_xor(p, 4);
        p += __shfl_xor(p, 8);
        if (lr == 0) out[r0 + lg * 4 + r] = sigm(p + lb2v);
    }
}

extern "C" void kernel_launch(void* const* d_in, const int* in_sizes, int n_in,
                              void* d_out, int out_size, void* d_ws, size_t ws_size,
                              hipStream_t stream) {
    const int*   pairs  = (const int*)d_in[0];
    const float* memory = (const float*)d_in[1];
    const float* w1  = (const float*)d_in[2];
    const float* b1  = (const float*)d_in[3];
    const float* w2  = (const float*)d_in[4];
    const float* b2  = (const float*)d_in[5];
    const float* wih = (const float*)d_in[6];
    const float* whh = (const float*)d_in[7];
    const float* bih = (const float*)d_in[8];
    const float* bhh = (const float*)d_in[9];
    const float* lw1 = (const float*)d_in[10];
    const float* lb1 = (const float*)d_in[11];
    const float* lw2 = (const float*)d_in[12];
    const float* lb2 = (const float*)d_in[13];
    unsigned short* wsb = (unsigned short*)d_ws;

    prep_weights<<<176, 256, 0, stream>>>(w1, w2, wih, whh, lw1, wsb);
    tgn_kernel<<<BATCH / 64, 256, 0, stream>>>(pairs, memory, wsb, b1, b2, bih, bhh,
                                               lb1, lw2, lb2, (float*)d_out);
}

// Round 5
// 185.356 us; speedup vs baseline: 1.4886x; 1.4886x over previous
//
#include <hip/hip_runtime.h>

#define BATCH 262144

typedef __attribute__((ext_vector_type(8))) short short8;
typedef __attribute__((ext_vector_type(4))) short s16x4;
typedef __attribute__((ext_vector_type(4))) float f32x4;

// float -> bf16 bits, round-to-nearest-even
static __device__ __forceinline__ short f2b(float f) {
    unsigned u = __float_as_uint(f);
    return (short)((u + 0x7fffu + ((u >> 16) & 1u)) >> 16);
}
static __device__ __forceinline__ float b2f(short s) {
    return __uint_as_float(((unsigned)(unsigned short)s) << 16);
}
static __device__ __forceinline__ float sigm(float x) { return 1.0f / (1.0f + __expf(-x)); }
static __device__ __forceinline__ float tanh_f(float x) { return 1.0f - 2.0f / (__expf(2.0f * x) + 1.0f); }

// All LDS buffers are PER-WAVE: no cross-wave sharing -> no __syncthreads needed.
// DS ops complete in order within a wave; lgkmcnt(0) makes prior ds_writes visible.
#define WAVE_FENCE() asm volatile("s_waitcnt lgkmcnt(0)" ::: "memory")

// XOR swizzle: unpadded rows, slot permutation per row -> 2 rows/slot = free 2-way.
// [16][64] bf16 tile: row stride 128 B.  [16][128] bf16 tile: row stride 256 B.
static __device__ __forceinline__ int sw128(int row, int cb) { return row * 128 + (cb ^ ((row & 7) << 4)); }
static __device__ __forceinline__ int sw256(int row, int cb) { return row * 256 + (cb ^ ((row & 7) << 4)); }

// Convert all weight matrices to bf16 in workspace.
// layout (bf16 elems): [0:8192) w1, [8192:12288) w2, [12288:24576) w_ih,
//                      [24576:36864) w_hh, [36864:45056) lp_w1
__global__ void prep_weights(const float* __restrict__ w1, const float* __restrict__ w2,
                             const float* __restrict__ wih, const float* __restrict__ whh,
                             const float* __restrict__ lw1, unsigned short* __restrict__ wsb) {
    int i = blockIdx.x * 256 + threadIdx.x;
    float v;
    if (i < 8192) v = w1[i];
    else if (i < 12288) v = w2[i - 8192];
    else if (i < 24576) v = wih[i - 12288];
    else if (i < 36864) v = whh[i - 24576];
    else if (i < 45056) v = lw1[i - 36864];
    else return;
    wsb[i] = (unsigned short)f2b(v);
}

// NOTE: no min-waves arg — __launch_bounds__(256,5) forced VGPR 64->48 and the
// compiler spilled to scratch (R4: WRITE_SIZE 361 MB, FETCH 4x). Natural alloc
// is ~64 VGPR <= 102 (=512/5), so 5 blocks/CU fit without forcing.
__global__ __launch_bounds__(256) void tgn_kernel(
    const int* __restrict__ pairs, const float* __restrict__ memory,
    const unsigned short* __restrict__ wsb,
    const float* __restrict__ b1, const float* __restrict__ b2,
    const float* __restrict__ bih, const float* __restrict__ bhh,
    const float* __restrict__ lb1, const float* __restrict__ lw2,
    const float* __restrict__ lb2, float* __restrict__ out)
{
    // 16384 + 16384 = 32768 B total -> 5 blocks/CU (5 * 32768 = 163840 = full pool)
    __shared__ __align__(16) char nmem[4][2][2048];  // n1/n2: [16][64] bf16 swizzled
    __shared__ __align__(16) char scr[4][4096];      // h1@0, msg@2048 ([16][64]); comb [16][128] overlays

    const int tid = threadIdx.x;
    const int w  = tid >> 6;
    const int l  = tid & 63;
    const int lr = l & 15;       // M/N index within fragment
    const int lg = l >> 4;       // k-group / row-group

    const int r0 = (blockIdx.x * 4 + w) * 16;

    char* n1b  = &nmem[w][0][0];
    char* n2b  = &nmem[w][1][0];
    char* h1b  = &scr[w][0];
    char* msgb = &scr[w][2048];
    char* comb = &scr[w][0];

    const unsigned short* w1b  = wsb;          // [64][128]
    const unsigned short* w2b  = wsb + 8192;   // [64][64]
    const unsigned short* wihb = wsb + 12288;  // [192][64]
    const unsigned short* whhb = wsb + 24576;  // [192][64]
    const unsigned short* lw1b = wsb + 36864;  // [64][128]

    const f32x4 z4 = {0.0f, 0.0f, 0.0f, 0.0f};

    // ---- stage 0: gather -> bf16 LDS. 16 lanes fetch one 256B memory row each ----
#pragma unroll
    for (int rr = 0; rr < 4; ++rr) {
        int row = rr * 4 + lg;
        long i1 = pairs[(r0 + row) * 2 + 0];
        long i2 = pairs[(r0 + row) * 2 + 1];
        f32x4 v1 = *(const f32x4*)(memory + i1 * 64 + lr * 4);
        f32x4 v2 = *(const f32x4*)(memory + i2 * 64 + lr * 4);
        s16x4 c1, c2;
#pragma unroll
        for (int j = 0; j < 4; ++j) { c1[j] = f2b(v1[j]); c2[j] = f2b(v2[j]); }
        int off = sw128(row, lr * 8);
        *(s16x4*)(n1b + off) = c1;
        *(s16x4*)(n2b + off) = c2;
    }
    WAVE_FENCE();

    // ---- stage 1: H1 = relu(X @ w1^T + b1), X = [n1|n2] (16x128) ----
    f32x4 acc[4];
#pragma unroll
    for (int nt = 0; nt < 4; ++nt) acc[nt] = z4;
#pragma unroll
    for (int kt = 0; kt < 4; ++kt) {
        const char* base = (kt < 2) ? n1b : n2b;
        short8 a = *(const short8*)(base + sw128(lr, (kt & 1) * 64 + lg * 16));
#pragma unroll
        for (int nt = 0; nt < 4; ++nt) {
            short8 b = *(const short8*)(w1b + (nt * 16 + lr) * 128 + kt * 32 + lg * 8);
            acc[nt] = __builtin_amdgcn_mfma_f32_16x16x32_bf16(a, b, acc[nt], 0, 0, 0);
        }
    }
#pragma unroll
    for (int nt = 0; nt < 4; ++nt) {
        float bv = b1[nt * 16 + lr];
#pragma unroll
        for (int r = 0; r < 4; ++r) {
            int row = lg * 4 + r;
            *(short*)(h1b + sw128(row, nt * 32 + lr * 2)) = f2b(fmaxf(acc[nt][r] + bv, 0.0f));
        }
    }
    WAVE_FENCE();

    // ---- stage 2: MSG = H1 @ w2^T + b2 (16x64) ----
#pragma unroll
    for (int nt = 0; nt < 4; ++nt) acc[nt] = z4;
#pragma unroll
    for (int kt = 0; kt < 2; ++kt) {
        short8 a = *(const short8*)(h1b + sw128(lr, kt * 64 + lg * 16));
#pragma unroll
        for (int nt = 0; nt < 4; ++nt) {
            short8 b = *(const short8*)(w2b + (nt * 16 + lr) * 64 + kt * 32 + lg * 8);
            acc[nt] = __builtin_amdgcn_mfma_f32_16x16x32_bf16(a, b, acc[nt], 0, 0, 0);
        }
    }
#pragma unroll
    for (int nt = 0; nt < 4; ++nt) {
        float bv = b2[nt * 16 + lr];
#pragma unroll
        for (int r = 0; r < 4; ++r) {
            int row = lg * 4 + r;
            *(short*)(msgb + sw128(row, nt * 32 + lr * 2)) = f2b(acc[nt][r] + bv);
        }
    }
    WAVE_FENCE();

    // ---- stage 3+4 fused: per column-block nt, compute 9 gate tiles then GRU ----
    short8 am[2], a1[2], a2[2];
#pragma unroll
    for (int kt = 0; kt < 2; ++kt) {
        am[kt] = *(const short8*)(msgb + sw128(lr, kt * 64 + lg * 16));
        a1[kt] = *(const short8*)(n1b + sw128(lr, kt * 64 + lg * 16));
        a2[kt] = *(const short8*)(n2b + sw128(lr, kt * 64 + lg * 16));
    }
#pragma unroll
    for (int nt = 0; nt < 4; ++nt) {
        f32x4 gir = z4, giz = z4, gin = z4;
        f32x4 g1r = z4, g1z = z4, g1n = z4;
        f32x4 g2r = z4, g2z = z4, g2n = z4;
#pragma unroll
        for (int kt = 0; kt < 2; ++kt) {
            int ko = kt * 32 + lg * 8;
            short8 bir = *(const short8*)(wihb + ((0 + nt) * 16 + lr) * 64 + ko);
            short8 biz = *(const short8*)(wihb + ((4 + nt) * 16 + lr) * 64 + ko);
            short8 bin = *(const short8*)(wihb + ((8 + nt) * 16 + lr) * 64 + ko);
            short8 bhr = *(const short8*)(whhb + ((0 + nt) * 16 + lr) * 64 + ko);
            short8 bhz = *(const short8*)(whhb + ((4 + nt) * 16 + lr) * 64 + ko);
            short8 bhn = *(const short8*)(whhb + ((8 + nt) * 16 + lr) * 64 + ko);
            gir = __builtin_amdgcn_mfma_f32_16x16x32_bf16(am[kt], bir, gir, 0, 0, 0);
            giz = __builtin_amdgcn_mfma_f32_16x16x32_bf16(am[kt], biz, giz, 0, 0, 0);
            gin = __builtin_amdgcn_mfma_f32_16x16x32_bf16(am[kt], bin, gin, 0, 0, 0);
            g1r = __builtin_amdgcn_mfma_f32_16x16x32_bf16(a1[kt], bhr, g1r, 0, 0, 0);
            g1z = __builtin_amdgcn_mfma_f32_16x16x32_bf16(a1[kt], bhz, g1z, 0, 0, 0);
            g1n = __builtin_amdgcn_mfma_f32_16x16x32_bf16(a1[kt], bhn, g1n, 0, 0, 0);
            g2r = __builtin_amdgcn_mfma_f32_16x16x32_bf16(a2[kt], bhr, g2r, 0, 0, 0);
            g2z = __builtin_amdgcn_mfma_f32_16x16x32_bf16(a2[kt], bhz, g2z, 0, 0, 0);
            g2n = __builtin_amdgcn_mfma_f32_16x16x32_bf16(a2[kt], bhn, g2n, 0, 0, 0);
        }
        int j = nt * 16 + lr;
        float bir_ = bih[j], biz_ = bih[64 + j], bin_ = bih[128 + j];
        float bhr_ = bhh[j], bhz_ = bhh[64 + j], bhn_ = bhh[128 + j];
#pragma unroll
        for (int r = 0; r < 4; ++r) {
            int row = lg * 4 + r;
            float i_r = gir[r] + bir_;
            float i_z = giz[r] + biz_;
            float i_n = gin[r] + bin_;
            // node 1
            float rg = sigm(i_r + g1r[r] + bhr_);
            float zg = sigm(i_z + g1z[r] + bhz_);
            float ng = tanh_f(i_n + rg * (g1n[r] + bhn_));
            float h  = b2f(*(const short*)(n1b + sw128(row, j * 2)));
            *(short*)(comb + sw256(row, j * 2)) = f2b((1.0f - zg) * ng + zg * h);
            // node 2
            rg = sigm(i_r + g2r[r] + bhr_);
            zg = sigm(i_z + g2z[r] + bhz_);
            ng = tanh_f(i_n + rg * (g2n[r] + bhn_));
            h  = b2f(*(const short*)(n2b + sw128(row, j * 2)));
            *(short*)(comb + sw256(row, 128 + j * 2)) = f2b((1.0f - zg) * ng + zg * h);
        }
    }
    WAVE_FENCE();

    // ---- stage 5: H = relu(COMB @ lp_w1^T + lb1) (16x64) ----
    f32x4 acc5[4];
#pragma unroll
    for (int nt = 0; nt < 4; ++nt) acc5[nt] = z4;
#pragma unroll
    for (int kt = 0; kt < 4; ++kt) {
        short8 a = *(const short8*)(comb + sw256(lr, kt * 64 + lg * 16));
#pragma unroll
        for (int nt = 0; nt < 4; ++nt) {
            short8 b = *(const short8*)(lw1b + (nt * 16 + lr) * 128 + kt * 32 + lg * 8);
            acc5[nt] = __builtin_amdgcn_mfma_f32_16x16x32_bf16(a, b, acc5[nt], 0, 0, 0);
        }
    }

    // ---- stage 6: out = sigmoid(H @ lp_w2^T + lb2), reduce over 64 cols ----
    float part[4] = {0.0f, 0.0f, 0.0f, 0.0f};
#pragma unroll
    for (int nt = 0; nt < 4; ++nt) {
        float w2v = lw2[nt * 16 + lr];
        float bv  = lb1[nt * 16 + lr];
#pragma unroll
        for (int r = 0; r < 4; ++r)
            part[r] += fmaxf(acc5[nt][r] + bv, 0.0f) * w2v;
    }
    float lb2v = lb2[0];
#pragma unroll
    for (int r = 0; r < 4; ++r) {
        float p = part[r];
        p += __shfl_xor(p, 1);
        p += __shfl_xor(p, 2);
        p += __shfl_xor(p, 4);
        p += __shfl_xor(p, 8);
        if (lr == 0) out[r0 + lg * 4 + r] = sigm(p + lb2v);
    }
}

extern "C" void kernel_launch(void* const* d_in, const int* in_sizes, int n_in,
                              void* d_out, int out_size, void* d_ws, size_t ws_size,
                              hipStream_t stream) {
    const int*   pairs  = (const int*)d_in[0];
    const float* memory = (const float*)d_in[1];
    const float* w1  = (const float*)d_in[2];
    const float* b1  = (const float*)d_in[3];
    const float* w2  = (const float*)d_in[4];
    const float* b2  = (const float*)d_in[5];
    const float* wih = (const float*)d_in[6];
    const float* whh = (const float*)d_in[7];
    const float* bih = (const float*)d_in[8];
    const float* bhh = (const float*)d_in[9];
    const float* lw1 = (const float*)d_in[10];
    const float* lb1 = (const float*)d_in[11];
    const float* lw2 = (const float*)d_in[12];
    const float* lb2 = (const float*)d_in[13];
    unsigned short* wsb = (unsigned short*)d_ws;

    prep_weights<<<176, 256, 0, stream>>>(w1, w2, wih, whh, lw1, wsb);
    tgn_kernel<<<BATCH / 64, 256, 0, stream>>>(pairs, memory, wsb, b1, b2, bih, bhh,
                                               lb1, lw2, lb2, (float*)d_out);
}